// Round 1
// baseline (464.194 us; speedup 1.0000x reference)
//
#include <hip/hip_runtime.h>
#include <hip/hip_bf16.h>

// DFTB Slater-Koster table interpolation.
// Inputs (setup_inputs order):
//   0: rij            [E=2,000,000] float32
//   1: edge_type      [E]           int32
//   2: atom_type      [N=500,000]   int32
//   3: hopping_tables [10,16,512]   float32
//   4: overlap_tables [10,16,512]   float32
//   5: onsiteE        [4,4]         float32
// Outputs (concatenated flat):
//   edge_features [E,16], edge_overlap [E,16], node_features [N,4]

#define NGRID 512
#define NUM_INGRLS 16

__global__ __launch_bounds__(256) void dftb_edge_kernel(
    const float* __restrict__ rij,
    const int*   __restrict__ etype,
    const float* __restrict__ hop,
    const float* __restrict__ ovl,
    float* __restrict__ out_hop,
    float* __restrict__ out_ovl,
    int E)
{
    const float X0f = 1.0f;
    const float DXf = (float)((10.0 - 1.0) / (NGRID - 1));

    int e = blockIdx.x * blockDim.x + threadIdx.x;
    if (e >= E) return;

    float r = rij[e];
    int   b = etype[e];

    float t  = (r - X0f) / DXf;
    int   i0 = (int)floorf(t);
    i0 = min(max(i0, 0), NGRID - 2);
    float frac = t - (float)i0;
    float w0   = 1.0f - frac;

    const float* hbase = hop + (size_t)b * (NUM_INGRLS * NGRID) + i0;
    const float* obase = ovl + (size_t)b * (NUM_INGRLS * NGRID) + i0;

    float oh[NUM_INGRLS];
    float oo[NUM_INGRLS];
#pragma unroll
    for (int m = 0; m < NUM_INGRLS; ++m) {
        float y0 = hbase[m * NGRID];
        float y1 = hbase[m * NGRID + 1];
        oh[m] = y0 * w0 + y1 * frac;
        float z0 = obase[m * NGRID];
        float z1 = obase[m * NGRID + 1];
        oo[m] = z0 * w0 + z1 * frac;
    }

    float4* oh4 = (float4*)(out_hop + (size_t)e * NUM_INGRLS);
    float4* oo4 = (float4*)(out_ovl + (size_t)e * NUM_INGRLS);
#pragma unroll
    for (int q = 0; q < 4; ++q) {
        oh4[q] = make_float4(oh[4*q+0], oh[4*q+1], oh[4*q+2], oh[4*q+3]);
        oo4[q] = make_float4(oo[4*q+0], oo[4*q+1], oo[4*q+2], oo[4*q+3]);
    }
}

__global__ __launch_bounds__(256) void dftb_node_kernel(
    const int*   __restrict__ atype,
    const float* __restrict__ onsiteE,   // [4,4] -> 4 float4 rows
    float* __restrict__ out,             // [N,4]
    int N)
{
    int n = blockIdx.x * blockDim.x + threadIdx.x;
    if (n >= N) return;
    int a = atype[n];
    const float4* src = (const float4*)onsiteE;
    ((float4*)out)[n] = src[a];
}

extern "C" void kernel_launch(void* const* d_in, const int* in_sizes, int n_in,
                              void* d_out, int out_size, void* d_ws, size_t ws_size,
                              hipStream_t stream) {
    const float* rij       = (const float*)d_in[0];
    const int*   edge_type = (const int*)  d_in[1];
    const int*   atom_type = (const int*)  d_in[2];
    const float* hop_tab   = (const float*)d_in[3];
    const float* ovl_tab   = (const float*)d_in[4];
    const float* onsiteE   = (const float*)d_in[5];

    const int E = in_sizes[0];
    const int N = in_sizes[2];

    float* out_hop  = (float*)d_out;
    float* out_ovl  = out_hop + (size_t)E * NUM_INGRLS;
    float* out_node = out_ovl + (size_t)E * NUM_INGRLS;

    {
        dim3 block(256);
        dim3 grid((E + 255) / 256);
        dftb_edge_kernel<<<grid, block, 0, stream>>>(
            rij, edge_type, hop_tab, ovl_tab, out_hop, out_ovl, E);
    }
    {
        dim3 block(256);
        dim3 grid((N + 255) / 256);
        dftb_node_kernel<<<grid, block, 0, stream>>>(
            atom_type, onsiteE, out_node, N);
    }
}